// Round 1
// baseline (545.042 us; speedup 1.0000x reference)
//
#include <hip/hip_runtime.h>

// BSplineBasis: T=262144 samples, K=512 cubic (DEGREE=3) basis functions.
// Output (T, 512) fp32 = 512 MiB, but only 4 entries per row are nonzero.
//
// Strategy: zero the whole output via hipMemsetAsync (rides the ROCr fill
// path, measured 6.29 TB/s on this chip => ~85 us for 512 MiB), then a tiny
// scatter kernel writes only the 4 nonzero basis values per row (~25 MB of
// HBM write traffic). The dense-write kernel this replaces achieved only
// ~1-3 TB/s effective on the same 512 MiB.

namespace {
constexpr int K_N  = 512;    // basis count (output columns)
constexpr int NKN  = 516;    // K + DEGREE + 1 knots
constexpr int DEG  = 3;
constexpr float EPSF = 1e-6f;
constexpr int BLK  = 256;    // threads per block (4 waves), 1 row per thread
}

__global__ __launch_bounds__(BLK)
void bspline_scatter_kernel(const float* __restrict__ t_arr,
                            const float* __restrict__ knots,
                            float* __restrict__ out, int n_rows)
{
    __shared__ float kv[NKN];
    for (int i = threadIdx.x; i < NKN; i += BLK) kv[i] = knots[i];
    __syncthreads();

    const int row = blockIdx.x * BLK + threadIdx.x;
    if (row >= n_rows) return;
    const float t = t_arr[row];

    // Reference semantics: degree-0 interval j=514 is [1,1] closed, but its
    // contribution dies at d=1 (kv[515]-kv[514]=0 < EPS), so t >= kv[512]
    // (i.e. t >= 1.0) yields an all-zero row. The memset already wrote the
    // zeros, so such rows need no work at all.
    if (!(t < kv[K_N])) return;

    // Largest s in [3, 511] with kv[s] <= t  =>  kv[s] <= t < kv[s+1],
    // identical fp32 comparisons to the reference's degree-0 test.
    // Adjacent rows share t-neighborhoods, so waves stay convergent and the
    // LDS reads broadcast.
    int lo = DEG, hi = K_N - 1;
    while (lo < hi) {
        const int mid = (lo + hi + 1) >> 1;
        if (t >= kv[mid]) lo = mid; else hi = mid - 1;
    }
    const int s = lo;

    // Local Cox-de Boor: N[k] = B_{s-d+k, d}(t), k = 0..d.
    // Arithmetic identical to the previously harness-verified kernel.
    float N[4] = {1.f, 0.f, 0.f, 0.f};
    #pragma unroll
    for (int d = 1; d <= DEG; ++d) {
        float nn[4];
        #pragma unroll
        for (int k = 0; k <= d; ++k) {
            const int j = s - d + k;
            const float left  = (k >= 1)     ? N[k - 1] : 0.f;  // B_{j,d-1}
            const float right = (k <= d - 1) ? N[k]     : 0.f;  // B_{j+1,d-1}
            const float den1 = kv[j + d]     - kv[j];
            const float den2 = kv[j + d + 1] - kv[j + 1];
            // Reference: where(den >= EPS, num/den, 0)
            const float c1 = (den1 >= EPSF) ? (t - kv[j]) / den1 : 0.f;
            const float c2 = (den2 >= EPSF) ? (kv[j + d + 1] - t) / den2 : 0.f;
            nn[k] = c1 * left + c2 * right;
        }
        #pragma unroll
        for (int k = 0; k <= d; ++k) N[k] = nn[k];
    }

    // First nonzero column j0 = s - DEG in [0, 508]; j0+3 <= 511, in bounds.
    float* p = out + (size_t)row * K_N + (s - DEG);
    p[0] = N[0]; p[1] = N[1]; p[2] = N[2]; p[3] = N[3];
}

extern "C" void kernel_launch(void* const* d_in, const int* in_sizes, int n_in,
                              void* d_out, int out_size, void* d_ws, size_t ws_size,
                              hipStream_t stream) {
    const float* t_arr = (const float*)d_in[0];
    const float* knots = (const float*)d_in[1];
    float* out = (float*)d_out;
    const int n_rows = in_sizes[0];              // 262144

    // Zero the whole dense output on the fast fill path (graph-capturable
    // memset node; ~6.3 TB/s measured on this chip for rocclr fills).
    hipMemsetAsync(out, 0, (size_t)n_rows * K_N * sizeof(float), stream);

    // Then scatter the 4 nonzero basis values per row.
    dim3 grid((n_rows + BLK - 1) / BLK);
    hipLaunchKernelGGL(bspline_scatter_kernel, grid, dim3(BLK), 0, stream,
                       t_arr, knots, out, n_rows);
}

// Round 3
// 519.809 us; speedup vs baseline: 1.0485x; 1.0485x over previous
//
#include <hip/hip_runtime.h>

// BSplineBasis: T=262144, K=512, DEGREE=3. Output (T,512) fp32 = 512 MiB,
// only 4 nonzeros per row. The harness re-poisons output+workspace inside the
// timed region (~355 us for a 2 GiB fill), so our job is to rewrite the
// 512 MiB output at the write-BW roofline (~6.3 TB/s => ~85 us).
//
// Design: one dense kernel. Phase 1: 16 threads compute the 4 nonzero values
// + start column j0 per row (bit-identical Cox-de Boor to the verified
// kernel). Phase 2: pure zero-store stream; the row index per float4 is
// wave-uniform and t is sorted, so the "this float4 overlaps the nonzero
// window" branch is wave-coherent and taken for <2% of stores. Nontemporal
// stores: output is never re-read and 512 MiB >> 32 MiB L2.

namespace {
constexpr int K_N  = 512;    // basis count (output columns)
constexpr int NKN  = 516;    // K + DEGREE + 1 knots
constexpr int DEG  = 3;
constexpr float EPSF = 1e-6f;
constexpr int ROWS = 16;     // rows per block
constexpr int BLK  = 256;    // threads per block (4 waves)

// Native clang vector type: __builtin_nontemporal_store requires a pointer to
// scalar or vector-of-scalar, not HIP's float4 class.
typedef float f32x4 __attribute__((ext_vector_type(4)));
}

__global__ __launch_bounds__(BLK)
void bspline_dense_kernel(const float* __restrict__ t_arr,
                          const float* __restrict__ knots,
                          float* __restrict__ out)
{
    __shared__ float kv[NKN];
    __shared__ float vals[ROWS][4];
    __shared__ int   j0s[ROWS];

    const int tid = threadIdx.x;
    for (int i = tid; i < NKN; i += BLK) kv[i] = knots[i];
    __syncthreads();

    const int row_base = blockIdx.x * ROWS;

    // Phase 1: threads 0..15 each compute the 4 nonzero basis values for one
    // row. Arithmetic identical to the harness-verified kernel.
    if (tid < ROWS) {
        const float t = t_arr[row_base + tid];
        int j0 = -16;                       // sentinel: all-zero row
        float N0 = 0.f, N1 = 0.f, N2 = 0.f, N3 = 0.f;
        // Reference: t >= kv[512] (t >= 1.0) yields an all-zero row.
        if (t < kv[K_N]) {
            // Largest s in [3, 511] with kv[s] <= t (same fp32 compares as ref).
            int lo = DEG, hi = K_N - 1;
            while (lo < hi) {
                const int mid = (lo + hi + 1) >> 1;
                if (t >= kv[mid]) lo = mid; else hi = mid - 1;
            }
            const int s = lo;
            float N[4] = {1.f, 0.f, 0.f, 0.f};
            #pragma unroll
            for (int d = 1; d <= DEG; ++d) {
                float nn[4];
                #pragma unroll
                for (int k = 0; k <= d; ++k) {
                    const int j = s - d + k;
                    const float left  = (k >= 1)     ? N[k - 1] : 0.f;
                    const float right = (k <= d - 1) ? N[k]     : 0.f;
                    const float den1 = kv[j + d]     - kv[j];
                    const float den2 = kv[j + d + 1] - kv[j + 1];
                    const float c1 = (den1 >= EPSF) ? (t - kv[j]) / den1 : 0.f;
                    const float c2 = (den2 >= EPSF) ? (kv[j + d + 1] - t) / den2 : 0.f;
                    nn[k] = c1 * left + c2 * right;
                }
                #pragma unroll
                for (int k = 0; k <= d; ++k) N[k] = nn[k];
            }
            j0 = s - DEG;
            N0 = N[0]; N1 = N[1]; N2 = N[2]; N3 = N[3];
        }
        j0s[tid] = j0;
        vals[tid][0] = N0; vals[tid][1] = N1;
        vals[tid][2] = N2; vals[tid][3] = N3;
    }
    __syncthreads();

    // Phase 2: dense coalesced float4 store stream. idx = it*256+tid:
    //   r = idx>>7 is wave-uniform (the branch below is wave-coherent)
    //   c = (tid&127)*4 is the float4's first column, constant across iters.
    f32x4* out4 = reinterpret_cast<f32x4*>(out + (size_t)row_base * K_N);
    const int c = (tid & 127) << 2;
    const f32x4 zero4 = {0.f, 0.f, 0.f, 0.f};
    constexpr int ITERS = ROWS * (K_N / 4) / BLK;   // 8
    #pragma unroll
    for (int it = 0; it < ITERS; ++it) {
        const int idx = it * BLK + tid;
        const int r   = idx >> 7;            // wave-uniform row
        const int rel = c - j0s[r];          // LDS broadcast read
        // Window [j0, j0+3] overlaps columns [c, c+3] iff -3 <= rel <= 3.
        // j0 = -16 sentinel => rel >= 16 => zero path. Wave-coherent branch.
        if (rel < -3 || rel > 3) {
            __builtin_nontemporal_store(zero4, &out4[idx]);
        } else {
            f32x4 e;
            #pragma unroll
            for (int k = 0; k < 4; ++k) {
                const int m = rel + k;               // value index for col c+k
                const float v = vals[r][m & 3];      // safe LDS read
                e[k] = (m >= 0 && m <= 3) ? v : 0.f;
            }
            __builtin_nontemporal_store(e, &out4[idx]);
        }
    }
}

extern "C" void kernel_launch(void* const* d_in, const int* in_sizes, int n_in,
                              void* d_out, int out_size, void* d_ws, size_t ws_size,
                              hipStream_t stream) {
    const float* t_arr = (const float*)d_in[0];
    const float* knots = (const float*)d_in[1];
    float* out = (float*)d_out;
    const int n_rows = in_sizes[0];              // 262144, divisible by ROWS
    dim3 grid(n_rows / ROWS);
    hipLaunchKernelGGL(bspline_dense_kernel, grid, dim3(BLK), 0, stream,
                       t_arr, knots, out);
}